// Round 2
// baseline (94.872 us; speedup 1.0000x reference)
//
#include <hip/hip_runtime.h>
#include <stdint.h>

// Problem constants (B,C,H,W)=(4,128,64,128), R=4, D=9, out channels 81.
// out[b, di*9+dj, h, w] = sum_c src[b,c,h,w] * tgt[b,c,h+di-8,w+dj-8]
// (zero when the shifted index leaves [0,H)x[0,W)).
#define NB 4
#define NC 128
#define NH 64
#define NW 128
#define HW (NH * NW)      // 8192
#define ND 9
#define NOUT (ND * ND)    // 81
#define CPW 32            // channels per wave (4 waves x 32 = 128)

// grid = 4*9*32 = 1152 blocks of 256 threads (4 waves).
//   slice = blockIdx>>5 : b = slice/9, di = slice%9
//   hp = blockIdx&31 : h = hp*2 + (lane>>5) ; w0 = (lane&31)*4
//   wave handles channels [wave*32, wave*32+32); LDS-reduce at epilogue.
//
// v3: window sharing via ds_bpermute as in v2, but the left-edge zeroing is
// done with integer AND masks on the bpermute RESULTS (pure dataflow), not
// ternaries. v2 failed because `q0 ? bpermute(...) : 0` compiled to an
// exec-masked branch; lanes 0,1,32,33 (q0/q1 false) were exec-disabled yet
// are the SOURCE lanes of other lanes' pulls -> undefined reads. With
// unconditional bpermutes the exec mask is the y>=0 mask, under which every
// source lane of an unmasked pull is provably active (halves deactivate
// lower-first, and in-half pulls never cross the half boundary unmasked).
__device__ __forceinline__ float pull_and(int byteidx, float v, int m) {
  return __int_as_float(__builtin_amdgcn_ds_bpermute(byteidx, __float_as_int(v)) & m);
}

__global__ __launch_bounds__(256, 4) void costvol_kernel(const float* __restrict__ src,
                                                         const float* __restrict__ tgt,
                                                         float* __restrict__ out) {
  const int tid  = threadIdx.x;
  const int lane = tid & 63;
  const int wave = tid >> 6;
  const int slice = blockIdx.x >> 5;       // 0..35
  const int di = slice % ND;               // 0..8
  const int b  = slice / ND;               // 0..3
  const int hp = blockIdx.x & 31;          // 0..31
  const int h  = (hp << 1) + (lane >> 5);  // 0..63
  const int w0 = (lane & 31) << 2;         // 0,4,...,124
  const int y  = h + di - 8;               // tgt row; <0 -> all-zero lane

  float acc[ND][4];
#pragma unroll
  for (int dj = 0; dj < ND; ++dj)
#pragma unroll
    for (int k = 0; k < 4; ++k) acc[dj][k] = 0.0f;

  // Window quads at cols w0-8 / w0-4 are all-in or all-out of bounds.
  // -1/0 integer masks (AND on pull results — no control flow).
  const int m0 = (w0 >= 8) ? -1 : 0;
  const int m1 = (w0 >= 4) ? -1 : 0;
  // bpermute byte indices: pull t2 quad of lane-2 (t0) and lane-1 (t1).
  const int i2 = ((lane - 2) & 63) << 2;
  const int i1 = ((lane - 1) & 63) << 2;

  if (y >= 0) {
    const float* spc = src + (size_t)((b * NC + wave * CPW) * NH + h) * NW + w0;
    const float* tpc = tgt + (size_t)((b * NC + wave * CPW) * NH + y) * NW + w0;

#pragma unroll 4
    for (int c = 0; c < CPW; ++c) {
      const float4 sv = *(const float4*)spc;
      const float4 t2 = *(const float4*)tpc;   // always in-bounds (w0 <= 124)

      float t[12];
      // t0 quad (cols w0-8..w0-5) = t2 of lane-2, zeroed for w0 < 8.
      t[0]  = pull_and(i2, t2.x, m0);
      t[1]  = pull_and(i2, t2.y, m0);
      t[2]  = pull_and(i2, t2.z, m0);
      t[3]  = pull_and(i2, t2.w, m0);
      // t1 quad (cols w0-4..w0-1) = t2 of lane-1, zeroed for w0 < 4.
      t[4]  = pull_and(i1, t2.x, m1);
      t[5]  = pull_and(i1, t2.y, m1);
      t[6]  = pull_and(i1, t2.z, m1);
      t[7]  = pull_and(i1, t2.w, m1);
      t[8]  = t2.x; t[9] = t2.y; t[10] = t2.z; t[11] = t2.w;

#pragma unroll
      for (int dj = 0; dj < ND; ++dj) {
        acc[dj][0] = fmaf(sv.x, t[dj + 0], acc[dj][0]);
        acc[dj][1] = fmaf(sv.y, t[dj + 1], acc[dj][1]);
        acc[dj][2] = fmaf(sv.z, t[dj + 2], acc[dj][2]);
        acc[dj][3] = fmaf(sv.w, t[dj + 3], acc[dj][3]);
      }

      spc += HW;
      tpc += HW;
    }
  }

  // Cross-wave reduction: each wave dumps acc to LDS, then 256 threads
  // sum the 4 copies and store. 4*9*64*4 floats = 36 KB.
  __shared__ float lds[4][ND][64][4];
#pragma unroll
  for (int dj = 0; dj < ND; ++dj) {
    float4 v;
    v.x = acc[dj][0]; v.y = acc[dj][1]; v.z = acc[dj][2]; v.w = acc[dj][3];
    *(float4*)&lds[wave][dj][lane][0] = v;
  }
  __syncthreads();

  for (int s = tid; s < ND * 64; s += 256) {
    const int dj = s >> 6;
    const int l  = s & 63;
    const float4 r0 = *(const float4*)&lds[0][dj][l][0];
    const float4 r1 = *(const float4*)&lds[1][dj][l][0];
    const float4 r2 = *(const float4*)&lds[2][dj][l][0];
    const float4 r3 = *(const float4*)&lds[3][dj][l][0];
    float4 o;
    o.x = (r0.x + r1.x) + (r2.x + r3.x);
    o.y = (r0.y + r1.y) + (r2.y + r3.y);
    o.z = (r0.z + r1.z) + (r2.z + r3.z);
    o.w = (r0.w + r1.w) + (r2.w + r3.w);
    const int hh = (hp << 1) + (l >> 5);
    const int ww = (l & 31) << 2;
    *(float4*)(out + (size_t)(((b * NOUT + di * ND + dj) * NH + hh) * NW + ww)) = o;
  }
}

extern "C" void kernel_launch(void* const* d_in, const int* in_sizes, int n_in,
                              void* d_out, int out_size, void* d_ws, size_t ws_size,
                              hipStream_t stream) {
  const float* src = (const float*)d_in[0];
  const float* tgt = (const float*)d_in[1];
  float* out = (float*)d_out;
  costvol_kernel<<<dim3(NB * ND * 32), dim3(256), 0, stream>>>(src, tgt, out);
}

// Round 3
// 92.924 us; speedup vs baseline: 1.0210x; 1.0210x over previous
//
#include <hip/hip_runtime.h>
#include <stdint.h>

// Problem constants (B,C,H,W)=(4,128,64,128), R=4, D=9, out channels 81.
// out[b, di*9+dj, h, w] = sum_c src[b,c,h,w] * tgt[b,c,h+di-8,w+dj-8]
// (zero when the shifted index leaves [0,H)x[0,W)).
#define NB 4
#define NC 128
#define NH 64
#define NW 128
#define HW (NH * NW)      // 8192
#define ND 9
#define NOUT (ND * ND)    // 81
#define CPW 32            // channels per wave (4 waves x 32 = 128)

// grid = 4*9*32 = 1152 blocks of 256 threads (4 waves).
// v4: XCD-aware work swizzle. All loads are L1-miss first-touches per
// block, ~295 MB of far-memory reads; a tgt row is re-read by 9 blocks
// with different hp, which the default blockIdx layout scatters across
// XCDs -> re-reads served by LLC (~6 TB/s observed) not L2 (34.5 TB/s).
// Remap so XCD (= blockIdx&7 under round-robin dispatch) pins a fixed
// (b, hp-half): working set 1 batch x 16 row-pairs = ~2 MB src + ~2.6 MB
// tgt window ~= one XCD's 4 MB L2 -> both 9x re-read streams become
// same-XCD L2 hits. Pure index permutation; dataflow unchanged from v3.
__device__ __forceinline__ float pull_and(int byteidx, float v, int m) {
  return __int_as_float(__builtin_amdgcn_ds_bpermute(byteidx, __float_as_int(v)) & m);
}

__global__ __launch_bounds__(256, 4) void costvol_kernel(const float* __restrict__ src,
                                                         const float* __restrict__ tgt,
                                                         float* __restrict__ out) {
  const int tid  = threadIdx.x;
  const int lane = tid & 63;
  const int wave = tid >> 6;

  // XCD-pinned decode: xcd = blockIdx&7 owns (b = xcd>>1, hp-half = xcd&1).
  // k enumerates that XCD's 144 blocks; di-inner so the 9 src-sharers of a
  // row-pair dispatch adjacently (tight temporal L2 reuse).
  const int xcd = blockIdx.x & 7;
  const int k   = blockIdx.x >> 3;         // 0..143
  const int b   = xcd >> 1;                // 0..3
  const int di  = k % ND;                  // 0..8
  const int hp  = ((xcd & 1) << 4) | (k / ND);  // 0..31

  const int h  = (hp << 1) + (lane >> 5);  // 0..63
  const int w0 = (lane & 31) << 2;         // 0,4,...,124
  const int y  = h + di - 8;               // tgt row; <0 -> all-zero lane

  float acc[ND][4];
#pragma unroll
  for (int dj = 0; dj < ND; ++dj)
#pragma unroll
    for (int kk = 0; kk < 4; ++kk) acc[dj][kk] = 0.0f;

  // Window quads at cols w0-8 / w0-4 are all-in or all-out of bounds.
  // -1/0 integer masks (AND on pull results — no control flow; bpermutes
  // must run unconditionally so source lanes stay exec-active).
  const int m0 = (w0 >= 8) ? -1 : 0;
  const int m1 = (w0 >= 4) ? -1 : 0;
  // bpermute byte indices: pull t2 quad of lane-2 (t0) and lane-1 (t1).
  const int i2 = ((lane - 2) & 63) << 2;
  const int i1 = ((lane - 1) & 63) << 2;

  if (y >= 0) {
    const float* spc = src + (size_t)((b * NC + wave * CPW) * NH + h) * NW + w0;
    const float* tpc = tgt + (size_t)((b * NC + wave * CPW) * NH + y) * NW + w0;

#pragma unroll 4
    for (int c = 0; c < CPW; ++c) {
      const float4 sv = *(const float4*)spc;
      const float4 t2 = *(const float4*)tpc;   // always in-bounds (w0 <= 124)

      float t[12];
      // t0 quad (cols w0-8..w0-5) = t2 of lane-2, zeroed for w0 < 8.
      // Wrapped pulls land only in masked (zeroed) results.
      t[0]  = pull_and(i2, t2.x, m0);
      t[1]  = pull_and(i2, t2.y, m0);
      t[2]  = pull_and(i2, t2.z, m0);
      t[3]  = pull_and(i2, t2.w, m0);
      // t1 quad (cols w0-4..w0-1) = t2 of lane-1, zeroed for w0 < 4.
      t[4]  = pull_and(i1, t2.x, m1);
      t[5]  = pull_and(i1, t2.y, m1);
      t[6]  = pull_and(i1, t2.z, m1);
      t[7]  = pull_and(i1, t2.w, m1);
      t[8]  = t2.x; t[9] = t2.y; t[10] = t2.z; t[11] = t2.w;

#pragma unroll
      for (int dj = 0; dj < ND; ++dj) {
        acc[dj][0] = fmaf(sv.x, t[dj + 0], acc[dj][0]);
        acc[dj][1] = fmaf(sv.y, t[dj + 1], acc[dj][1]);
        acc[dj][2] = fmaf(sv.z, t[dj + 2], acc[dj][2]);
        acc[dj][3] = fmaf(sv.w, t[dj + 3], acc[dj][3]);
      }

      spc += HW;
      tpc += HW;
    }
  }

  // Cross-wave reduction: each wave dumps acc to LDS, then 256 threads
  // sum the 4 copies and store. 4*9*64*4 floats = 36 KB.
  __shared__ float lds[4][ND][64][4];
#pragma unroll
  for (int dj = 0; dj < ND; ++dj) {
    float4 v;
    v.x = acc[dj][0]; v.y = acc[dj][1]; v.z = acc[dj][2]; v.w = acc[dj][3];
    *(float4*)&lds[wave][dj][lane][0] = v;
  }
  __syncthreads();

  for (int s = tid; s < ND * 64; s += 256) {
    const int dj = s >> 6;
    const int l  = s & 63;
    const float4 r0 = *(const float4*)&lds[0][dj][l][0];
    const float4 r1 = *(const float4*)&lds[1][dj][l][0];
    const float4 r2 = *(const float4*)&lds[2][dj][l][0];
    const float4 r3 = *(const float4*)&lds[3][dj][l][0];
    float4 o;
    o.x = (r0.x + r1.x) + (r2.x + r3.x);
    o.y = (r0.y + r1.y) + (r2.y + r3.y);
    o.z = (r0.z + r1.z) + (r2.z + r3.z);
    o.w = (r0.w + r1.w) + (r2.w + r3.w);
    const int hh = (hp << 1) + (l >> 5);
    const int ww = (l & 31) << 2;
    *(float4*)(out + (size_t)(((b * NOUT + di * ND + dj) * NH + hh) * NW + ww)) = o;
  }
}

extern "C" void kernel_launch(void* const* d_in, const int* in_sizes, int n_in,
                              void* d_out, int out_size, void* d_ws, size_t ws_size,
                              hipStream_t stream) {
  const float* src = (const float*)d_in[0];
  const float* tgt = (const float*)d_in[1];
  float* out = (float*)d_out;
  costvol_kernel<<<dim3(NB * ND * 32), dim3(256), 0, stream>>>(src, tgt, out);
}